// Round 4
// baseline (355.659 us; speedup 1.0000x reference)
//
#include <hip/hip_runtime.h>
#include <hip/hip_bf16.h>
#include <stdint.h>

#define N_NODES 8192
#define N_EDGES 262144
#define IN_F 512
#define HID 512
#define OUT_F 256
#define CAP 128   // raw append capacity per node; Poisson(32) max ~70, P(>128)~0

typedef __attribute__((ext_vector_type(8))) short short8;
typedef __attribute__((ext_vector_type(4))) float f32x4;

// ---------- bf16 helpers (RNE) ----------
__device__ __forceinline__ float bflo(unsigned int u) {
  union { unsigned int x; float f; } c; c.x = u << 16; return c.f;
}
__device__ __forceinline__ float bfhi(unsigned int u) {
  union { unsigned int x; float f; } c; c.x = u & 0xffff0000u; return c.f;
}
__device__ __forceinline__ float bf1(unsigned short s) {
  union { unsigned int x; float f; } c; c.x = (unsigned int)s << 16; return c.f;
}
__device__ __forceinline__ unsigned short f2bf(float f) {
  union { float f; unsigned int u; } c; c.f = f;
  unsigned int r = c.u + 0x7fffu + ((c.u >> 16) & 1u);
  return (unsigned short)(r >> 16);
}

__device__ __forceinline__ void gload_lds16(const void* g, void* l) {
  __builtin_amdgcn_global_load_lds((const __attribute__((address_space(1))) void*)g,
                                   (__attribute__((address_space(3))) void*)l, 16, 0, 0);
}

// ---------- fused prep: X->bf16 | W1^T->bf16 | W2^T->bf16 | edge append ----------
#define NB_CVT  4096
#define NB_W1   1024
#define NB_W2    512
#define NB_EDGE 1024
__global__ __launch_bounds__(256) void prep_all(
    const float* __restrict__ x, const float* __restrict__ W1, const float* __restrict__ W2,
    const int* __restrict__ ei,
    unsigned short* __restrict__ Xb, unsigned short* __restrict__ W1t,
    unsigned short* __restrict__ W2t, int* __restrict__ cnt, int* __restrict__ adj) {
  const int b = blockIdx.x, tid = threadIdx.x;
  if (b < NB_CVT) {
    int idx = b * 256 + tid;
    const float4 v = ((const float4*)x)[idx];
    uint2 o;
    o.x = (unsigned int)f2bf(v.x) | ((unsigned int)f2bf(v.y) << 16);
    o.y = (unsigned int)f2bf(v.z) | ((unsigned int)f2bf(v.w) << 16);
    ((uint2*)Xb)[idx] = o;
  } else if (b < NB_CVT + NB_W1) {
    int idx = (b - NB_CVT) * 256 + tid;
    int k = idx >> 9, n = idx & 511;
    W1t[n * IN_F + k] = f2bf(W1[idx]);
  } else if (b < NB_CVT + NB_W1 + NB_W2) {
    int idx = (b - NB_CVT - NB_W1) * 256 + tid;
    int k = idx >> 8, n = idx & 255;
    W2t[n * HID + k] = f2bf(W2[idx]);
  } else {
    int e = (b - NB_CVT - NB_W1 - NB_W2) * 256 + tid;
    int i = ei[e];
    int j = ei[N_EDGES + e];
    int p = atomicAdd(&cnt[i], 1);
    if (p < CAP) adj[i * CAP + p] = j;
  }
}

// ---------- per-node dedup (+ degree -> dis) ----------
__global__ __launch_bounds__(128) void dedup_node(
    int* __restrict__ cnt, int* __restrict__ adj, float* __restrict__ dis) {
  const int i = blockIdx.x, t = threadIdx.x;
  __shared__ int js[CAP];
  __shared__ unsigned char keep[CAP];
  int n0 = cnt[i]; if (n0 > CAP) n0 = CAP;
  if (t < n0) js[t] = adj[i * CAP + t];
  __syncthreads();
  bool k = false;
  if (t < n0) {
    k = true;
    int jt = js[t];
    for (int s = 0; s < t; ++s) if (js[s] == jt) { k = false; break; }
  }
  keep[t] = k;
  __syncthreads();
  if (k) {
    int r = 0;
    for (int s = 0; s < t; ++s) r += keep[s];
    adj[i * CAP + r] = js[t];
  }
  if (t == 0) {
    int nd = 0;
    for (int s = 0; s < n0; ++s) nd += keep[s];
    cnt[i] = nd;
    dis[i] = rsqrtf((float)(nd + 1));
  }
}

// ---------- bf16 MFMA GEMM with diagnostic repeat (idempotent) ----------
template<int BM, int BN>
__global__ __launch_bounds__(256) void gemm_bt(
    const unsigned short* __restrict__ A, const unsigned short* __restrict__ Bt,
    unsigned short* __restrict__ C, int M, int N, int K, int reps) {
  constexpr int MR = BM / 32, NR = BN / 32;
  __shared__ __align__(16) unsigned short As[BM * 64];
  __shared__ __align__(16) unsigned short Bs[BN * 64];
  const int tid = threadIdx.x;
  const long row0 = (long)blockIdx.x * BM;
  const long col0 = (long)blockIdx.y * BN;
  const int lane = tid & 63;
  const int wid = tid >> 6;
  const int ln15 = lane & 15, hi = lane >> 4;
  const int wr = (wid >> 1) * (BM / 2), wc = (wid & 1) * (BN / 2);
  const int sr = tid >> 3;
  const int sk = (tid & 7) * 8;

  for (int rep = 0; rep < reps; ++rep) {
    f32x4 acc[MR][NR] = {};
    for (int k0 = 0; k0 < K; k0 += 64) {
#pragma unroll
      for (int c = 0; c < MR; ++c)
        gload_lds16(A  + (row0 + c * 32 + sr) * (long)K + k0 + sk, &As[(c * 256 + tid) * 8]);
#pragma unroll
      for (int c = 0; c < NR; ++c)
        gload_lds16(Bt + (col0 + c * 32 + sr) * (long)K + k0 + sk, &Bs[(c * 256 + tid) * 8]);
      __syncthreads();
#pragma unroll
      for (int kk = 0; kk < 64; kk += 32) {
        short8 a[MR], b[NR];
#pragma unroll
        for (int m = 0; m < MR; ++m)
          a[m] = *(const short8*)&As[(wr + m * 16 + ln15) * 64 + kk + hi * 8];
#pragma unroll
        for (int n = 0; n < NR; ++n)
          b[n] = *(const short8*)&Bs[(wc + n * 16 + ln15) * 64 + kk + hi * 8];
#pragma unroll
        for (int m = 0; m < MR; ++m)
#pragma unroll
          for (int n = 0; n < NR; ++n)
            acc[m][n] = __builtin_amdgcn_mfma_f32_16x16x32_bf16(a[m], b[n], acc[m][n], 0, 0, 0);
      }
      __syncthreads();
    }
#pragma unroll
    for (int m = 0; m < MR; ++m)
#pragma unroll
      for (int n = 0; n < NR; ++n)
#pragma unroll
        for (int r = 0; r < 4; ++r) {
          long row = row0 + wr + m * 16 + hi * 4 + r;
          long col = col0 + wc + n * 16 + ln15;
          C[row * N + col] = f2bf(acc[m][n][r]);
        }
    __syncthreads();
  }
}

// ---------- layer-1 aggregation (R2 shape: single pass, uint4 16B/lane) ----------
__global__ __launch_bounds__(256) void aggregate_relu(
    const unsigned short* __restrict__ T, const int* __restrict__ cnt,
    const int* __restrict__ adj, const float* __restrict__ dis,
    const float* __restrict__ bias, unsigned short* __restrict__ H, int reps) {
  const int i = blockIdx.x;
  const int tid = threadIdx.x;
  const int lane = tid & 63, w = tid >> 6;
  __shared__ int js[CAP];
  __shared__ float ws[CAP];
  __shared__ float part[4][512];
  int n = cnt[i];
  if (tid < n) { int j = adj[i * CAP + tid]; js[tid] = j; ws[tid] = dis[j]; }
  __syncthreads();
  const float di = dis[i];
  for (int rep = 0; rep < reps; ++rep) {
    float a[8] = {};
    for (int e = w; e < n; e += 4) {
      const uint4 v = *(const uint4*)&T[(long)js[e] * 512 + lane * 8];
      float wj = ws[e];
      a[0] += wj * bflo(v.x); a[1] += wj * bfhi(v.x);
      a[2] += wj * bflo(v.y); a[3] += wj * bfhi(v.y);
      a[4] += wj * bflo(v.z); a[5] += wj * bfhi(v.z);
      a[6] += wj * bflo(v.w); a[7] += wj * bfhi(v.w);
    }
    *(float4*)&part[w][lane * 8]     = make_float4(a[0], a[1], a[2], a[3]);
    *(float4*)&part[w][lane * 8 + 4] = make_float4(a[4], a[5], a[6], a[7]);
    __syncthreads();
    unsigned int u = *(const unsigned int*)&T[(long)i * 512 + tid * 2];
    float s0 = part[0][2*tid]   + part[1][2*tid]   + part[2][2*tid]   + part[3][2*tid]   + di * bflo(u);
    float s1 = part[0][2*tid+1] + part[1][2*tid+1] + part[2][2*tid+1] + part[3][2*tid+1] + di * bfhi(u);
    const float2 bb = *(const float2*)&bias[2 * tid];
    float h0 = fmaxf(di * s0 + bb.x, 0.f);
    float h1 = fmaxf(di * s1 + bb.y, 0.f);
    *(unsigned int*)&H[(long)i * 512 + tid * 2] =
        (unsigned int)f2bf(h0) | ((unsigned int)f2bf(h1) << 16);
    __syncthreads();
  }
}

// ---------- layer-2 aggregation (single pass, uint2 8B/lane) ----------
__global__ __launch_bounds__(256) void aggregate_out(
    const unsigned short* __restrict__ T, const int* __restrict__ cnt,
    const int* __restrict__ adj, const float* __restrict__ dis,
    const float* __restrict__ bias, float* __restrict__ out, int reps) {
  const int i = blockIdx.x;
  const int tid = threadIdx.x;
  const int lane = tid & 63, w = tid >> 6;
  __shared__ int js[CAP];
  __shared__ float ws[CAP];
  __shared__ float part[4][256];
  int n = cnt[i];
  if (tid < n) { int j = adj[i * CAP + tid]; js[tid] = j; ws[tid] = dis[j]; }
  __syncthreads();
  const float di = dis[i];
  for (int rep = 0; rep < reps; ++rep) {
    float a[4] = {};
    for (int e = w; e < n; e += 4) {
      const uint2 v = *(const uint2*)&T[(long)js[e] * 256 + lane * 4];
      float wj = ws[e];
      a[0] += wj * bflo(v.x); a[1] += wj * bfhi(v.x);
      a[2] += wj * bflo(v.y); a[3] += wj * bfhi(v.y);
    }
    *(float4*)&part[w][lane * 4] = make_float4(a[0], a[1], a[2], a[3]);
    __syncthreads();
    float self = di * bf1(T[(long)i * 256 + tid]);
    float s = part[0][tid] + part[1][tid] + part[2][tid] + part[3][tid] + self;
    out[(long)i * 256 + tid] = di * s + bias[tid];
    __syncthreads();
  }
}

extern "C" void kernel_launch(void* const* d_in, const int* in_sizes, int n_in,
                              void* d_out, int out_size, void* d_ws, size_t ws_size,
                              hipStream_t stream) {
  const float* x  = (const float*)d_in[0];
  const int*   ei = (const int*)d_in[1];
  const float* W1 = (const float*)d_in[2];
  const float* b1 = (const float*)d_in[3];
  const float* W2 = (const float*)d_in[4];
  const float* b2 = (const float*)d_in[5];
  float* out = (float*)d_out;

  char* ws = (char*)d_ws;
  int* cnt   = (int*)ws;                     ws += 32768;
  int* adj   = (int*)ws;                     ws += (size_t)N_NODES * CAP * 4;
  float* dis = (float*)ws;                   ws += 32768;
  unsigned short* Xb  = (unsigned short*)ws; ws += (size_t)N_NODES * IN_F * 2;
  unsigned short* W1t = (unsigned short*)ws; ws += (size_t)IN_F * HID * 2;
  unsigned short* W2t = (unsigned short*)ws; ws += (size_t)HID * OUT_F * 2;
  unsigned short* T1  = (unsigned short*)ws; ws += (size_t)N_NODES * HID * 2;
  unsigned short* H   = (unsigned short*)ws; ws += (size_t)N_NODES * HID * 2;
  unsigned short* T2  = (unsigned short*)ws; ws += (size_t)N_NODES * OUT_F * 2;

  hipMemsetAsync(cnt, 0, 32768, stream);

  prep_all<<<NB_CVT + NB_W1 + NB_W2 + NB_EDGE, 256, 0, stream>>>(
      x, W1, W2, ei, Xb, W1t, W2t, cnt, adj);
  dedup_node<<<N_NODES, 128, 0, stream>>>(cnt, adj, dis);

  // DIAGNOSTIC ROUND: reps>1 on the four main kernels (idempotent re-compute)
  // to surface each in rocprof top-5 with its own counters. true_cost = dur/reps.
  gemm_bt<128, 64><<<dim3(N_NODES / 128, HID / 64), 256, 0, stream>>>(
      Xb, W1t, T1, N_NODES, HID, IN_F, 8);
  aggregate_relu<<<N_NODES, 256, 0, stream>>>(T1, cnt, adj, dis, b1, H, 4);

  gemm_bt<64, 64><<<dim3(N_NODES / 64, OUT_F / 64), 256, 0, stream>>>(
      H, W2t, T2, N_NODES, OUT_F, HID, 8);
  aggregate_out<<<N_NODES, 256, 0, stream>>>(T2, cnt, adj, dis, b2, out, 4);
}

// Round 5
// 162.423 us; speedup vs baseline: 2.1897x; 2.1897x over previous
//
#include <hip/hip_runtime.h>
#include <hip/hip_bf16.h>
#include <stdint.h>

#define N_NODES 8192
#define N_EDGES 262144
#define IN_F 512
#define HID 512
#define OUT_F 256
#define CAP 128   // raw append capacity per node; Poisson(32), P(>128)~0

typedef __attribute__((ext_vector_type(8))) short short8;
typedef __attribute__((ext_vector_type(4))) float f32x4;

// ---------- bf16 helpers (RNE) ----------
__device__ __forceinline__ float bflo(unsigned int u) {
  union { unsigned int x; float f; } c; c.x = u << 16; return c.f;
}
__device__ __forceinline__ float bfhi(unsigned int u) {
  union { unsigned int x; float f; } c; c.x = u & 0xffff0000u; return c.f;
}
__device__ __forceinline__ unsigned short f2bf(float f) {
  union { float f; unsigned int u; } c; c.f = f;
  unsigned int r = c.u + 0x7fffu + ((c.u >> 16) & 1u);
  return (unsigned short)(r >> 16);
}

__device__ __forceinline__ void gload_lds16(const void* g, void* l) {
  __builtin_amdgcn_global_load_lds((const __attribute__((address_space(1))) void*)g,
                                   (__attribute__((address_space(3))) void*)l, 16, 0, 0);
}

// ---------- fused prep: X->bf16 | W1^T (LDS tiles) | W2^T | edge append ----------
#define NB_CVT  4096           // 8192*512/4 float4 / 256
#define NB_W1T  64             // (512/64)*(512/64) tiles
#define NB_W2T  32             // (512/64)*(256/64)
#define NB_EDGE 1024           // 262144/256

__device__ __forceinline__ void transpose_tile64(
    const float* __restrict__ W, unsigned short* __restrict__ Wt,
    int K, int N, int kb, int nb, int tid, float (*tile)[65]) {
  const int k0g = kb * 64, n0g = nb * 64;
  const int r = tid >> 4;          // 0..15
  const int c4 = (tid & 15) * 4;   // 0..60
#pragma unroll
  for (int rr = 0; rr < 4; ++rr) {
    const int k = rr * 16 + r;
    const float4 v = *(const float4*)&W[(size_t)(k0g + k) * N + n0g + c4];
    tile[k][c4] = v.x; tile[k][c4 + 1] = v.y; tile[k][c4 + 2] = v.z; tile[k][c4 + 3] = v.w;
  }
  __syncthreads();
  const int n = tid >> 2;          // 0..63
  const int kq = (tid & 3) * 16;   // 0,16,32,48
  unsigned int o[8];
#pragma unroll
  for (int q = 0; q < 8; ++q) {
    unsigned int lo = f2bf(tile[kq + 2 * q][n]);
    unsigned int hi = f2bf(tile[kq + 2 * q + 1][n]);
    o[q] = lo | (hi << 16);
  }
  unsigned int* dst = (unsigned int*)&Wt[(size_t)(n0g + n) * K + k0g + kq];
  *(uint4*)dst       = make_uint4(o[0], o[1], o[2], o[3]);
  *(uint4*)(dst + 4) = make_uint4(o[4], o[5], o[6], o[7]);
}

__global__ __launch_bounds__(256) void prep_all(
    const float* __restrict__ x, const float* __restrict__ W1, const float* __restrict__ W2,
    const int* __restrict__ ei,
    unsigned short* __restrict__ Xb, unsigned short* __restrict__ W1t,
    unsigned short* __restrict__ W2t, int* __restrict__ cnt, int* __restrict__ adj) {
  __shared__ float tile[64][65];
  const int b = blockIdx.x, tid = threadIdx.x;
  if (b < NB_CVT) {
    int idx = b * 256 + tid;
    const float4 v = ((const float4*)x)[idx];
    uint2 o;
    o.x = (unsigned int)f2bf(v.x) | ((unsigned int)f2bf(v.y) << 16);
    o.y = (unsigned int)f2bf(v.z) | ((unsigned int)f2bf(v.w) << 16);
    ((uint2*)Xb)[idx] = o;
  } else if (b < NB_CVT + NB_W1T) {
    int t = b - NB_CVT;                       // W1 512x512: 8x8 tiles
    transpose_tile64(W1, W1t, IN_F, HID, t >> 3, t & 7, tid, tile);
  } else if (b < NB_CVT + NB_W1T + NB_W2T) {
    int t = b - NB_CVT - NB_W1T;              // W2 512x256: 8x4 tiles
    transpose_tile64(W2, W2t, HID, OUT_F, t >> 2, t & 3, tid, tile);
  } else {
    int e = (b - NB_CVT - NB_W1T - NB_W2T) * 256 + tid;
    int i = ei[e];
    int j = ei[N_EDGES + e];
    int p = atomicAdd(&cnt[i], 1);
    if (p < CAP) adj[i * CAP + p] = j;
  }
}

// ---------- per-node dedup (+ degree -> dis) ----------
__global__ __launch_bounds__(128) void dedup_node(
    int* __restrict__ cnt, int* __restrict__ adj, float* __restrict__ dis) {
  const int i = blockIdx.x, t = threadIdx.x;
  __shared__ int js[CAP];
  __shared__ unsigned char keep[CAP];
  int n0 = cnt[i]; if (n0 > CAP) n0 = CAP;
  if (t < n0) js[t] = adj[i * CAP + t];
  __syncthreads();
  bool k = false;
  if (t < n0) {
    k = true;
    int jt = js[t];
    for (int s = 0; s < t; ++s) if (js[s] == jt) { k = false; break; }
  }
  keep[t] = k;
  __syncthreads();
  if (k) {
    int r = 0;
    for (int s = 0; s < t; ++s) r += keep[s];
    adj[i * CAP + r] = js[t];
  }
  if (t == 0) {
    int nd = 0;
    for (int s = 0; s < n0; ++s) nd += keep[s];
    cnt[i] = nd;
    dis[i] = rsqrtf((float)(nd + 1));
  }
}

// ---------- bf16 MFMA GEMM: C[M,N] = A[M,K] @ Bt[N,K]^T ----------
template<int BM, int BN>
__global__ __launch_bounds__(256) void gemm_bt(
    const unsigned short* __restrict__ A, const unsigned short* __restrict__ Bt,
    unsigned short* __restrict__ C, int M, int N, int K) {
  constexpr int MR = BM / 32, NR = BN / 32;
  __shared__ __align__(16) unsigned short As[BM * 64];
  __shared__ __align__(16) unsigned short Bs[BN * 64];
  const int tid = threadIdx.x;
  const long row0 = (long)blockIdx.x * BM;
  const long col0 = (long)blockIdx.y * BN;
  const int lane = tid & 63;
  const int wid = tid >> 6;
  const int ln15 = lane & 15, hi = lane >> 4;
  const int wr = (wid >> 1) * (BM / 2), wc = (wid & 1) * (BN / 2);
  const int sr = tid >> 3;
  const int sk = (tid & 7) * 8;
  f32x4 acc[MR][NR] = {};

  for (int k0 = 0; k0 < K; k0 += 64) {
#pragma unroll
    for (int c = 0; c < MR; ++c)
      gload_lds16(A  + (row0 + c * 32 + sr) * (long)K + k0 + sk, &As[(c * 256 + tid) * 8]);
#pragma unroll
    for (int c = 0; c < NR; ++c)
      gload_lds16(Bt + (col0 + c * 32 + sr) * (long)K + k0 + sk, &Bs[(c * 256 + tid) * 8]);
    __syncthreads();
#pragma unroll
    for (int kk = 0; kk < 64; kk += 32) {
      short8 a[MR], b[NR];
#pragma unroll
      for (int m = 0; m < MR; ++m)
        a[m] = *(const short8*)&As[(wr + m * 16 + ln15) * 64 + kk + hi * 8];
#pragma unroll
      for (int n = 0; n < NR; ++n)
        b[n] = *(const short8*)&Bs[(wc + n * 16 + ln15) * 64 + kk + hi * 8];
#pragma unroll
      for (int m = 0; m < MR; ++m)
#pragma unroll
        for (int n = 0; n < NR; ++n)
          acc[m][n] = __builtin_amdgcn_mfma_f32_16x16x32_bf16(a[m], b[n], acc[m][n], 0, 0, 0);
    }
    __syncthreads();
  }
#pragma unroll
  for (int m = 0; m < MR; ++m)
#pragma unroll
    for (int n = 0; n < NR; ++n)
#pragma unroll
      for (int r = 0; r < 4; ++r) {
        long row = row0 + wr + m * 16 + hi * 4 + r;
        long col = col0 + wc + n * 16 + ln15;
        C[row * N + col] = f2bf(acc[m][n][r]);
      }
}

// ---------- layer-1 aggregation: ONE WAVE PER NODE ----------
// out_i = di*(sum_j dj*T_j + di*T_i) + b, relu. Lane holds 8 of 512 feats (uint4).
__global__ __launch_bounds__(256) void aggregate_relu(
    const unsigned short* __restrict__ T, const int* __restrict__ cnt,
    const int* __restrict__ adj, const float* __restrict__ dis,
    const float* __restrict__ bias, unsigned short* __restrict__ H) {
  const int w = threadIdx.x >> 6, lane = threadIdx.x & 63;
  const int i = blockIdx.x * 4 + w;
  __shared__ uint2 jw[4][CAP];           // {j, bits(dis[j])}
  const int n = cnt[i];
  for (int e0 = 0; e0 < n; e0 += 64)
    if (e0 + lane < n) {
      int j = adj[i * CAP + e0 + lane];
      jw[w][e0 + lane] = make_uint2((unsigned int)j, __float_as_uint(dis[j]));
    }
  __syncthreads();
  float a[8] = {};
  const float di = dis[i];
  int e = 0;
  for (; e + 2 <= n; e += 2) {
    const uint2 p0 = jw[w][e], p1 = jw[w][e + 1];
    const uint4 v0 = *(const uint4*)&T[(size_t)p0.x * 512 + lane * 8];
    const uint4 v1 = *(const uint4*)&T[(size_t)p1.x * 512 + lane * 8];
    const float w0 = __uint_as_float(p0.y), w1 = __uint_as_float(p1.y);
    a[0] += w0 * bflo(v0.x); a[1] += w0 * bfhi(v0.x);
    a[2] += w0 * bflo(v0.y); a[3] += w0 * bfhi(v0.y);
    a[4] += w0 * bflo(v0.z); a[5] += w0 * bfhi(v0.z);
    a[6] += w0 * bflo(v0.w); a[7] += w0 * bfhi(v0.w);
    a[0] += w1 * bflo(v1.x); a[1] += w1 * bfhi(v1.x);
    a[2] += w1 * bflo(v1.y); a[3] += w1 * bfhi(v1.y);
    a[4] += w1 * bflo(v1.z); a[5] += w1 * bfhi(v1.z);
    a[6] += w1 * bflo(v1.w); a[7] += w1 * bfhi(v1.w);
  }
  if (e < n) {
    const uint2 p0 = jw[w][e];
    const uint4 v0 = *(const uint4*)&T[(size_t)p0.x * 512 + lane * 8];
    const float w0 = __uint_as_float(p0.y);
    a[0] += w0 * bflo(v0.x); a[1] += w0 * bfhi(v0.x);
    a[2] += w0 * bflo(v0.y); a[3] += w0 * bfhi(v0.y);
    a[4] += w0 * bflo(v0.z); a[5] += w0 * bfhi(v0.z);
    a[6] += w0 * bflo(v0.w); a[7] += w0 * bfhi(v0.w);
  }
  {  // self-loop term (+I stacked on top of any explicit self-edge)
    const uint4 vs = *(const uint4*)&T[(size_t)i * 512 + lane * 8];
    a[0] += di * bflo(vs.x); a[1] += di * bfhi(vs.x);
    a[2] += di * bflo(vs.y); a[3] += di * bfhi(vs.y);
    a[4] += di * bflo(vs.z); a[5] += di * bfhi(vs.z);
    a[6] += di * bflo(vs.w); a[7] += di * bfhi(vs.w);
  }
  const float4 b0 = *(const float4*)&bias[lane * 8];
  const float4 b1 = *(const float4*)&bias[lane * 8 + 4];
  float h[8];
  h[0] = fmaxf(di * a[0] + b0.x, 0.f); h[1] = fmaxf(di * a[1] + b0.y, 0.f);
  h[2] = fmaxf(di * a[2] + b0.z, 0.f); h[3] = fmaxf(di * a[3] + b0.w, 0.f);
  h[4] = fmaxf(di * a[4] + b1.x, 0.f); h[5] = fmaxf(di * a[5] + b1.y, 0.f);
  h[6] = fmaxf(di * a[6] + b1.z, 0.f); h[7] = fmaxf(di * a[7] + b1.w, 0.f);
  uint4 o;
  o.x = (unsigned int)f2bf(h[0]) | ((unsigned int)f2bf(h[1]) << 16);
  o.y = (unsigned int)f2bf(h[2]) | ((unsigned int)f2bf(h[3]) << 16);
  o.z = (unsigned int)f2bf(h[4]) | ((unsigned int)f2bf(h[5]) << 16);
  o.w = (unsigned int)f2bf(h[6]) | ((unsigned int)f2bf(h[7]) << 16);
  *(uint4*)&H[(size_t)i * 512 + lane * 8] = o;
}

// ---------- layer-2 aggregation: ONE WAVE PER NODE (256 feats, uint2/lane) ----------
__global__ __launch_bounds__(256) void aggregate_out(
    const unsigned short* __restrict__ T, const int* __restrict__ cnt,
    const int* __restrict__ adj, const float* __restrict__ dis,
    const float* __restrict__ bias, float* __restrict__ out) {
  const int w = threadIdx.x >> 6, lane = threadIdx.x & 63;
  const int i = blockIdx.x * 4 + w;
  __shared__ uint2 jw[4][CAP];
  const int n = cnt[i];
  for (int e0 = 0; e0 < n; e0 += 64)
    if (e0 + lane < n) {
      int j = adj[i * CAP + e0 + lane];
      jw[w][e0 + lane] = make_uint2((unsigned int)j, __float_as_uint(dis[j]));
    }
  __syncthreads();
  float a[4] = {};
  const float di = dis[i];
  int e = 0;
  for (; e + 2 <= n; e += 2) {
    const uint2 p0 = jw[w][e], p1 = jw[w][e + 1];
    const uint2 v0 = *(const uint2*)&T[(size_t)p0.x * 256 + lane * 4];
    const uint2 v1 = *(const uint2*)&T[(size_t)p1.x * 256 + lane * 4];
    const float w0 = __uint_as_float(p0.y), w1 = __uint_as_float(p1.y);
    a[0] += w0 * bflo(v0.x); a[1] += w0 * bfhi(v0.x);
    a[2] += w0 * bflo(v0.y); a[3] += w0 * bfhi(v0.y);
    a[0] += w1 * bflo(v1.x); a[1] += w1 * bfhi(v1.x);
    a[2] += w1 * bflo(v1.y); a[3] += w1 * bfhi(v1.y);
  }
  if (e < n) {
    const uint2 p0 = jw[w][e];
    const uint2 v0 = *(const uint2*)&T[(size_t)p0.x * 256 + lane * 4];
    const float w0 = __uint_as_float(p0.y);
    a[0] += w0 * bflo(v0.x); a[1] += w0 * bfhi(v0.x);
    a[2] += w0 * bflo(v0.y); a[3] += w0 * bfhi(v0.y);
  }
  {
    const uint2 vs = *(const uint2*)&T[(size_t)i * 256 + lane * 4];
    a[0] += di * bflo(vs.x); a[1] += di * bfhi(vs.x);
    a[2] += di * bflo(vs.y); a[3] += di * bfhi(vs.y);
  }
  const float4 bb = *(const float4*)&bias[lane * 4];
  float4 o;
  o.x = di * a[0] + bb.x;
  o.y = di * a[1] + bb.y;
  o.z = di * a[2] + bb.z;
  o.w = di * a[3] + bb.w;
  *(float4*)&out[(size_t)i * 256 + lane * 4] = o;
}

extern "C" void kernel_launch(void* const* d_in, const int* in_sizes, int n_in,
                              void* d_out, int out_size, void* d_ws, size_t ws_size,
                              hipStream_t stream) {
  const float* x  = (const float*)d_in[0];
  const int*   ei = (const int*)d_in[1];
  const float* W1 = (const float*)d_in[2];
  const float* b1 = (const float*)d_in[3];
  const float* W2 = (const float*)d_in[4];
  const float* b2 = (const float*)d_in[5];
  float* out = (float*)d_out;

  char* ws = (char*)d_ws;
  int* cnt   = (int*)ws;                     ws += 32768;
  int* adj   = (int*)ws;                     ws += (size_t)N_NODES * CAP * 4;
  float* dis = (float*)ws;                   ws += 32768;
  unsigned short* Xb  = (unsigned short*)ws; ws += (size_t)N_NODES * IN_F * 2;
  unsigned short* W1t = (unsigned short*)ws; ws += (size_t)IN_F * HID * 2;
  unsigned short* W2t = (unsigned short*)ws; ws += (size_t)HID * OUT_F * 2;
  unsigned short* T1  = (unsigned short*)ws; ws += (size_t)N_NODES * HID * 2;
  unsigned short* H   = (unsigned short*)ws; ws += (size_t)N_NODES * HID * 2;
  unsigned short* T2  = (unsigned short*)ws; ws += (size_t)N_NODES * OUT_F * 2;

  hipMemsetAsync(cnt, 0, 32768, stream);

  prep_all<<<NB_CVT + NB_W1T + NB_W2T + NB_EDGE, 256, 0, stream>>>(
      x, W1, W2, ei, Xb, W1t, W2t, cnt, adj);
  dedup_node<<<N_NODES, 128, 0, stream>>>(cnt, adj, dis);

  // layer 1: T1 = X @ W1 ; H = relu(Ahat * T1 + b1)
  gemm_bt<128, 64><<<dim3(N_NODES / 128, HID / 64), 256, 0, stream>>>(Xb, W1t, T1, N_NODES, HID, IN_F);
  aggregate_relu<<<N_NODES / 4, 256, 0, stream>>>(T1, cnt, adj, dis, b1, H);

  // layer 2: T2 = H @ W2 ; out = Ahat * T2 + b2
  gemm_bt<64, 64><<<dim3(N_NODES / 64, OUT_F / 64), 256, 0, stream>>>(H, W2t, T2, N_NODES, OUT_F, HID);
  aggregate_out<<<N_NODES / 4, 256, 0, stream>>>(T2, cnt, adj, dis, b2, out);
}

// Round 6
// 160.762 us; speedup vs baseline: 2.2123x; 1.0103x over previous
//
#include <hip/hip_runtime.h>
#include <hip/hip_bf16.h>
#include <stdint.h>

#define N_NODES 8192
#define N_EDGES 262144
#define IN_F 512
#define HID 512
#define OUT_F 256
#define CAP 128   // distinct out-neighbors capacity; Poisson(32), P(>128)~0

typedef __attribute__((ext_vector_type(8))) short short8;
typedef __attribute__((ext_vector_type(4))) float f32x4;

// ---------- bf16 helpers (RNE) ----------
__device__ __forceinline__ float bflo(unsigned int u) {
  union { unsigned int x; float f; } c; c.x = u << 16; return c.f;
}
__device__ __forceinline__ float bfhi(unsigned int u) {
  union { unsigned int x; float f; } c; c.x = u & 0xffff0000u; return c.f;
}
__device__ __forceinline__ unsigned short f2bf(float f) {
  union { float f; unsigned int u; } c; c.f = f;
  unsigned int r = c.u + 0x7fffu + ((c.u >> 16) & 1u);
  return (unsigned short)(r >> 16);
}

__device__ __forceinline__ void gload_lds16(const void* g, void* l) {
  __builtin_amdgcn_global_load_lds((const __attribute__((address_space(1))) void*)g,
                                   (__attribute__((address_space(3))) void*)l, 16, 0, 0);
}

// ---------- fused prep: X->bf16 | W1^T (LDS tiles) | W2^T | edge append w/ bitmap dedup ----------
#define NB_CVT  4096           // 8192*512/4 float4 / 256
#define NB_W1T  64             // (512/64)*(512/64) tiles
#define NB_W2T  32             // (512/64)*(256/64)
#define NB_EDGE 1024           // 262144/256

__device__ __forceinline__ void transpose_tile64(
    const float* __restrict__ W, unsigned short* __restrict__ Wt,
    int K, int N, int kb, int nb, int tid, float (*tile)[65]) {
  const int k0g = kb * 64, n0g = nb * 64;
  const int r = tid >> 4;          // 0..15
  const int c4 = (tid & 15) * 4;   // 0..60
#pragma unroll
  for (int rr = 0; rr < 4; ++rr) {
    const int k = rr * 16 + r;
    const float4 v = *(const float4*)&W[(size_t)(k0g + k) * N + n0g + c4];
    tile[k][c4] = v.x; tile[k][c4 + 1] = v.y; tile[k][c4 + 2] = v.z; tile[k][c4 + 3] = v.w;
  }
  __syncthreads();
  const int n = tid >> 2;          // 0..63
  const int kq = (tid & 3) * 16;   // 0,16,32,48
  unsigned int o[8];
#pragma unroll
  for (int q = 0; q < 8; ++q) {
    unsigned int lo = f2bf(tile[kq + 2 * q][n]);
    unsigned int hi = f2bf(tile[kq + 2 * q + 1][n]);
    o[q] = lo | (hi << 16);
  }
  unsigned int* dst = (unsigned int*)&Wt[(size_t)(n0g + n) * K + k0g + kq];
  *(uint4*)dst       = make_uint4(o[0], o[1], o[2], o[3]);
  *(uint4*)(dst + 4) = make_uint4(o[4], o[5], o[6], o[7]);
}

__global__ __launch_bounds__(256) void prep_all(
    const float* __restrict__ x, const float* __restrict__ W1, const float* __restrict__ W2,
    const int* __restrict__ ei,
    unsigned short* __restrict__ Xb, unsigned short* __restrict__ W1t,
    unsigned short* __restrict__ W2t, unsigned int* __restrict__ bitmap,
    int* __restrict__ cnt, int* __restrict__ adj) {
  __shared__ float tile[64][65];
  const int b = blockIdx.x, tid = threadIdx.x;
  if (b < NB_CVT) {
    int idx = b * 256 + tid;
    const float4 v = ((const float4*)x)[idx];
    uint2 o;
    o.x = (unsigned int)f2bf(v.x) | ((unsigned int)f2bf(v.y) << 16);
    o.y = (unsigned int)f2bf(v.z) | ((unsigned int)f2bf(v.w) << 16);
    ((uint2*)Xb)[idx] = o;
  } else if (b < NB_CVT + NB_W1T) {
    int t = b - NB_CVT;                       // W1 512x512: 8x8 tiles
    transpose_tile64(W1, W1t, IN_F, HID, t >> 3, t & 7, tid, tile);
  } else if (b < NB_CVT + NB_W1T + NB_W2T) {
    int t = b - NB_CVT - NB_W1T;              // W2 512x256: 8x4 tiles
    transpose_tile64(W2, W2t, HID, OUT_F, t >> 2, t & 3, tid, tile);
  } else {
    // edge append with dedup-at-insert: only the bit-flipping thread appends,
    // so adj[i][*] ends up holding the DISTINCT out-neighbors of i.
    int e = (b - NB_CVT - NB_W1T - NB_W2T) * 256 + tid;
    int i = ei[e];
    int j = ei[N_EDGES + e];
    int lin = i * N_NODES + j;
    unsigned int bit = 1u << (lin & 31);
    unsigned int old = atomicOr(&bitmap[lin >> 5], bit);
    if (!(old & bit)) {
      int p = atomicAdd(&cnt[i], 1);
      if (p < CAP) adj[i * CAP + p] = j;
    }
  }
}

// ---------- bf16 MFMA GEMM: C[M,N] = A[M,K] @ Bt[N,K]^T ----------
template<int BM, int BN>
__global__ __launch_bounds__(256) void gemm_bt(
    const unsigned short* __restrict__ A, const unsigned short* __restrict__ Bt,
    unsigned short* __restrict__ C, int M, int N, int K) {
  constexpr int MR = BM / 32, NR = BN / 32;
  __shared__ __align__(16) unsigned short As[BM * 64];
  __shared__ __align__(16) unsigned short Bs[BN * 64];
  const int tid = threadIdx.x;
  const long row0 = (long)blockIdx.x * BM;
  const long col0 = (long)blockIdx.y * BN;
  const int lane = tid & 63;
  const int wid = tid >> 6;
  const int ln15 = lane & 15, hi = lane >> 4;
  const int wr = (wid >> 1) * (BM / 2), wc = (wid & 1) * (BN / 2);
  const int sr = tid >> 3;
  const int sk = (tid & 7) * 8;
  f32x4 acc[MR][NR] = {};

  for (int k0 = 0; k0 < K; k0 += 64) {
#pragma unroll
    for (int c = 0; c < MR; ++c)
      gload_lds16(A  + (row0 + c * 32 + sr) * (long)K + k0 + sk, &As[(c * 256 + tid) * 8]);
#pragma unroll
    for (int c = 0; c < NR; ++c)
      gload_lds16(Bt + (col0 + c * 32 + sr) * (long)K + k0 + sk, &Bs[(c * 256 + tid) * 8]);
    __syncthreads();
#pragma unroll
    for (int kk = 0; kk < 64; kk += 32) {
      short8 a[MR], b[NR];
#pragma unroll
      for (int m = 0; m < MR; ++m)
        a[m] = *(const short8*)&As[(wr + m * 16 + ln15) * 64 + kk + hi * 8];
#pragma unroll
      for (int n = 0; n < NR; ++n)
        b[n] = *(const short8*)&Bs[(wc + n * 16 + ln15) * 64 + kk + hi * 8];
#pragma unroll
      for (int m = 0; m < MR; ++m)
#pragma unroll
        for (int n = 0; n < NR; ++n)
          acc[m][n] = __builtin_amdgcn_mfma_f32_16x16x32_bf16(a[m], b[n], acc[m][n], 0, 0, 0);
    }
    __syncthreads();
  }
#pragma unroll
  for (int m = 0; m < MR; ++m)
#pragma unroll
    for (int n = 0; n < NR; ++n)
#pragma unroll
      for (int r = 0; r < 4; ++r) {
        long row = row0 + wr + m * 16 + hi * 4 + r;
        long col = col0 + wc + n * 16 + ln15;
        C[row * N + col] = f2bf(acc[m][n][r]);
      }
}

// ---------- layer-1 aggregation: ONE WAVE PER NODE, dis computed on the fly ----------
// out_i = di*(sum_j dj*T_j + di*T_i) + b, relu. Lane holds 8 of 512 feats (uint4).
__global__ __launch_bounds__(256) void aggregate_relu(
    const unsigned short* __restrict__ T, const int* __restrict__ cnt,
    const int* __restrict__ adj, const float* __restrict__ bias,
    unsigned short* __restrict__ H) {
  const int w = threadIdx.x >> 6, lane = threadIdx.x & 63;
  const int i = blockIdx.x * 4 + w;
  __shared__ uint2 jw[4][CAP];           // {j, bits(dis_j)}
  const int n = cnt[i];
  for (int e0 = 0; e0 < n; e0 += 64)
    if (e0 + lane < n) {
      int j = adj[i * CAP + e0 + lane];
      float dj = rsqrtf((float)(cnt[j] + 1));
      jw[w][e0 + lane] = make_uint2((unsigned int)j, __float_as_uint(dj));
    }
  __syncthreads();
  float a[8] = {};
  const float di = rsqrtf((float)(n + 1));
  int e = 0;
  for (; e + 2 <= n; e += 2) {
    const uint2 p0 = jw[w][e], p1 = jw[w][e + 1];
    const uint4 v0 = *(const uint4*)&T[(size_t)p0.x * 512 + lane * 8];
    const uint4 v1 = *(const uint4*)&T[(size_t)p1.x * 512 + lane * 8];
    const float w0 = __uint_as_float(p0.y), w1 = __uint_as_float(p1.y);
    a[0] += w0 * bflo(v0.x); a[1] += w0 * bfhi(v0.x);
    a[2] += w0 * bflo(v0.y); a[3] += w0 * bfhi(v0.y);
    a[4] += w0 * bflo(v0.z); a[5] += w0 * bfhi(v0.z);
    a[6] += w0 * bflo(v0.w); a[7] += w0 * bfhi(v0.w);
    a[0] += w1 * bflo(v1.x); a[1] += w1 * bfhi(v1.x);
    a[2] += w1 * bflo(v1.y); a[3] += w1 * bfhi(v1.y);
    a[4] += w1 * bflo(v1.z); a[5] += w1 * bfhi(v1.z);
    a[6] += w1 * bflo(v1.w); a[7] += w1 * bfhi(v1.w);
  }
  if (e < n) {
    const uint2 p0 = jw[w][e];
    const uint4 v0 = *(const uint4*)&T[(size_t)p0.x * 512 + lane * 8];
    const float w0 = __uint_as_float(p0.y);
    a[0] += w0 * bflo(v0.x); a[1] += w0 * bfhi(v0.x);
    a[2] += w0 * bflo(v0.y); a[3] += w0 * bfhi(v0.y);
    a[4] += w0 * bflo(v0.z); a[5] += w0 * bfhi(v0.z);
    a[6] += w0 * bflo(v0.w); a[7] += w0 * bfhi(v0.w);
  }
  {  // self-loop (+I), stacks with any explicit self-edge handled in the loop
    const uint4 vs = *(const uint4*)&T[(size_t)i * 512 + lane * 8];
    a[0] += di * bflo(vs.x); a[1] += di * bfhi(vs.x);
    a[2] += di * bflo(vs.y); a[3] += di * bfhi(vs.y);
    a[4] += di * bflo(vs.z); a[5] += di * bfhi(vs.z);
    a[6] += di * bflo(vs.w); a[7] += di * bfhi(vs.w);
  }
  const float4 b0 = *(const float4*)&bias[lane * 8];
  const float4 b1 = *(const float4*)&bias[lane * 8 + 4];
  float h[8];
  h[0] = fmaxf(di * a[0] + b0.x, 0.f); h[1] = fmaxf(di * a[1] + b0.y, 0.f);
  h[2] = fmaxf(di * a[2] + b0.z, 0.f); h[3] = fmaxf(di * a[3] + b0.w, 0.f);
  h[4] = fmaxf(di * a[4] + b1.x, 0.f); h[5] = fmaxf(di * a[5] + b1.y, 0.f);
  h[6] = fmaxf(di * a[6] + b1.z, 0.f); h[7] = fmaxf(di * a[7] + b1.w, 0.f);
  uint4 o;
  o.x = (unsigned int)f2bf(h[0]) | ((unsigned int)f2bf(h[1]) << 16);
  o.y = (unsigned int)f2bf(h[2]) | ((unsigned int)f2bf(h[3]) << 16);
  o.z = (unsigned int)f2bf(h[4]) | ((unsigned int)f2bf(h[5]) << 16);
  o.w = (unsigned int)f2bf(h[6]) | ((unsigned int)f2bf(h[7]) << 16);
  *(uint4*)&H[(size_t)i * 512 + lane * 8] = o;
}

// ---------- layer-2 aggregation: ONE WAVE PER NODE (256 feats, uint2/lane) ----------
__global__ __launch_bounds__(256) void aggregate_out(
    const unsigned short* __restrict__ T, const int* __restrict__ cnt,
    const int* __restrict__ adj, const float* __restrict__ bias,
    float* __restrict__ out) {
  const int w = threadIdx.x >> 6, lane = threadIdx.x & 63;
  const int i = blockIdx.x * 4 + w;
  __shared__ uint2 jw[4][CAP];
  const int n = cnt[i];
  for (int e0 = 0; e0 < n; e0 += 64)
    if (e0 + lane < n) {
      int j = adj[i * CAP + e0 + lane];
      float dj = rsqrtf((float)(cnt[j] + 1));
      jw[w][e0 + lane] = make_uint2((unsigned int)j, __float_as_uint(dj));
    }
  __syncthreads();
  float a[4] = {};
  const float di = rsqrtf((float)(n + 1));
  int e = 0;
  for (; e + 2 <= n; e += 2) {
    const uint2 p0 = jw[w][e], p1 = jw[w][e + 1];
    const uint2 v0 = *(const uint2*)&T[(size_t)p0.x * 256 + lane * 4];
    const uint2 v1 = *(const uint2*)&T[(size_t)p1.x * 256 + lane * 4];
    const float w0 = __uint_as_float(p0.y), w1 = __uint_as_float(p1.y);
    a[0] += w0 * bflo(v0.x); a[1] += w0 * bfhi(v0.x);
    a[2] += w0 * bflo(v0.y); a[3] += w0 * bfhi(v0.y);
    a[0] += w1 * bflo(v1.x); a[1] += w1 * bfhi(v1.x);
    a[2] += w1 * bflo(v1.y); a[3] += w1 * bfhi(v1.y);
  }
  if (e < n) {
    const uint2 p0 = jw[w][e];
    const uint2 v0 = *(const uint2*)&T[(size_t)p0.x * 256 + lane * 4];
    const float w0 = __uint_as_float(p0.y);
    a[0] += w0 * bflo(v0.x); a[1] += w0 * bfhi(v0.x);
    a[2] += w0 * bflo(v0.y); a[3] += w0 * bfhi(v0.y);
  }
  {
    const uint2 vs = *(const uint2*)&T[(size_t)i * 256 + lane * 4];
    a[0] += di * bflo(vs.x); a[1] += di * bfhi(vs.x);
    a[2] += di * bflo(vs.y); a[3] += di * bfhi(vs.y);
  }
  const float4 bb = *(const float4*)&bias[lane * 4];
  float4 o;
  o.x = di * a[0] + bb.x;
  o.y = di * a[1] + bb.y;
  o.z = di * a[2] + bb.z;
  o.w = di * a[3] + bb.w;
  *(float4*)&out[(size_t)i * 256 + lane * 4] = o;
}

extern "C" void kernel_launch(void* const* d_in, const int* in_sizes, int n_in,
                              void* d_out, int out_size, void* d_ws, size_t ws_size,
                              hipStream_t stream) {
  const float* x  = (const float*)d_in[0];
  const int*   ei = (const int*)d_in[1];
  const float* W1 = (const float*)d_in[2];
  const float* b1 = (const float*)d_in[3];
  const float* W2 = (const float*)d_in[4];
  const float* b2 = (const float*)d_in[5];
  float* out = (float*)d_out;

  char* ws = (char*)d_ws;
  unsigned int* bitmap = (unsigned int*)ws;  ws += 8388608;              // 8192^2 bits
  int* cnt   = (int*)ws;                     ws += 32768;
  int* adj   = (int*)ws;                     ws += (size_t)N_NODES * CAP * 4;
  unsigned short* Xb  = (unsigned short*)ws; ws += (size_t)N_NODES * IN_F * 2;
  unsigned short* W1t = (unsigned short*)ws; ws += (size_t)IN_F * HID * 2;
  unsigned short* W2t = (unsigned short*)ws; ws += (size_t)HID * OUT_F * 2;
  unsigned short* T1  = (unsigned short*)ws; ws += (size_t)N_NODES * HID * 2;
  unsigned short* H   = (unsigned short*)ws; ws += (size_t)N_NODES * HID * 2;
  unsigned short* T2  = (unsigned short*)ws; ws += (size_t)N_NODES * OUT_F * 2;

  hipMemsetAsync(bitmap, 0, 8388608 + 32768, stream);  // bitmap + cnt contiguous

  prep_all<<<NB_CVT + NB_W1T + NB_W2T + NB_EDGE, 256, 0, stream>>>(
      x, W1, W2, ei, Xb, W1t, W2t, bitmap, cnt, adj);

  // layer 1: T1 = X @ W1 ; H = relu(Ahat * T1 + b1)
  gemm_bt<128, 64><<<dim3(N_NODES / 128, HID / 64), 256, 0, stream>>>(Xb, W1t, T1, N_NODES, HID, IN_F);
  aggregate_relu<<<N_NODES / 4, 256, 0, stream>>>(T1, cnt, adj, b1, H);

  // layer 2: T2 = H @ W2 ; out = Ahat * T2 + b2
  gemm_bt<64, 64><<<dim3(N_NODES / 64, OUT_F / 64), 256, 0, stream>>>(H, W2t, T2, N_NODES, OUT_F, HID);
  aggregate_out<<<N_NODES / 4, 256, 0, stream>>>(T2, cnt, adj, b2, out);
}

// Round 7
// 160.010 us; speedup vs baseline: 2.2227x; 1.0047x over previous
//
#include <hip/hip_runtime.h>
#include <hip/hip_bf16.h>
#include <stdint.h>

#define N_NODES 8192
#define N_EDGES 262144
#define IN_F 512
#define HID 512
#define OUT_F 256
#define CAP 128   // distinct out-neighbors capacity; Poisson(32), P(>128)~0

typedef __attribute__((ext_vector_type(8))) short short8;
typedef __attribute__((ext_vector_type(4))) float f32x4;

// ---------- bf16 helpers (RNE) ----------
__device__ __forceinline__ float bflo(unsigned int u) {
  union { unsigned int x; float f; } c; c.x = u << 16; return c.f;
}
__device__ __forceinline__ float bfhi(unsigned int u) {
  union { unsigned int x; float f; } c; c.x = u & 0xffff0000u; return c.f;
}
__device__ __forceinline__ unsigned short f2bf(float f) {
  union { float f; unsigned int u; } c; c.f = f;
  unsigned int r = c.u + 0x7fffu + ((c.u >> 16) & 1u);
  return (unsigned short)(r >> 16);
}

__device__ __forceinline__ void gload_lds16(const void* g, void* l) {
  __builtin_amdgcn_global_load_lds((const __attribute__((address_space(1))) void*)g,
                                   (__attribute__((address_space(3))) void*)l, 16, 0, 0);
}

// ---------- fused prep: X->bf16 | W1^T (LDS tiles) | W2^T | edge append w/ bitmap dedup ----------
#define NB_CVT  4096           // 8192*512/4 float4 / 256
#define NB_W1T  64             // (512/64)*(512/64) tiles
#define NB_W2T  32             // (512/64)*(256/64)
#define NB_EDGE 1024           // 262144/256

__device__ __forceinline__ void transpose_tile64(
    const float* __restrict__ W, unsigned short* __restrict__ Wt,
    int K, int N, int kb, int nb, int tid, float (*tile)[65]) {
  const int k0g = kb * 64, n0g = nb * 64;
  const int r = tid >> 4;          // 0..15
  const int c4 = (tid & 15) * 4;   // 0..60
#pragma unroll
  for (int rr = 0; rr < 4; ++rr) {
    const int k = rr * 16 + r;
    const float4 v = *(const float4*)&W[(size_t)(k0g + k) * N + n0g + c4];
    tile[k][c4] = v.x; tile[k][c4 + 1] = v.y; tile[k][c4 + 2] = v.z; tile[k][c4 + 3] = v.w;
  }
  __syncthreads();
  const int n = tid >> 2;          // 0..63
  const int kq = (tid & 3) * 16;   // 0,16,32,48
  unsigned int o[8];
#pragma unroll
  for (int q = 0; q < 8; ++q) {
    unsigned int lo = f2bf(tile[kq + 2 * q][n]);
    unsigned int hi = f2bf(tile[kq + 2 * q + 1][n]);
    o[q] = lo | (hi << 16);
  }
  unsigned int* dst = (unsigned int*)&Wt[(size_t)(n0g + n) * K + k0g + kq];
  *(uint4*)dst       = make_uint4(o[0], o[1], o[2], o[3]);
  *(uint4*)(dst + 4) = make_uint4(o[4], o[5], o[6], o[7]);
}

__global__ __launch_bounds__(256) void prep_all(
    const float* __restrict__ x, const float* __restrict__ W1, const float* __restrict__ W2,
    const int* __restrict__ ei,
    unsigned short* __restrict__ Xb, unsigned short* __restrict__ W1t,
    unsigned short* __restrict__ W2t, unsigned int* __restrict__ bitmap,
    int* __restrict__ cnt, int* __restrict__ adj) {
  __shared__ float tile[64][65];
  const int b = blockIdx.x, tid = threadIdx.x;
  if (b < NB_CVT) {
    int idx = b * 256 + tid;
    const float4 v = ((const float4*)x)[idx];
    uint2 o;
    o.x = (unsigned int)f2bf(v.x) | ((unsigned int)f2bf(v.y) << 16);
    o.y = (unsigned int)f2bf(v.z) | ((unsigned int)f2bf(v.w) << 16);
    ((uint2*)Xb)[idx] = o;
  } else if (b < NB_CVT + NB_W1T) {
    int t = b - NB_CVT;                       // W1 512x512: 8x8 tiles
    transpose_tile64(W1, W1t, IN_F, HID, t >> 3, t & 7, tid, tile);
  } else if (b < NB_CVT + NB_W1T + NB_W2T) {
    int t = b - NB_CVT - NB_W1T;              // W2 512x256: 8x4 tiles
    transpose_tile64(W2, W2t, HID, OUT_F, t >> 2, t & 3, tid, tile);
  } else {
    // edge append with dedup-at-insert: only the bit-flipping thread appends,
    // so adj[i][*] holds the DISTINCT out-neighbors of i.
    int e = (b - NB_CVT - NB_W1T - NB_W2T) * 256 + tid;
    int i = ei[e];
    int j = ei[N_EDGES + e];
    int lin = i * N_NODES + j;
    unsigned int bit = 1u << (lin & 31);
    unsigned int old = atomicOr(&bitmap[lin >> 5], bit);
    if (!(old & bit)) {
      int p = atomicAdd(&cnt[i], 1);
      if (p < CAP) adj[i * CAP + p] = j;
    }
  }
}

// ---------- bf16 MFMA GEMM: C[M,N] = A[M,K] @ Bt[N,K]^T ----------
template<int BM, int BN>
__global__ __launch_bounds__(256) void gemm_bt(
    const unsigned short* __restrict__ A, const unsigned short* __restrict__ Bt,
    unsigned short* __restrict__ C, int M, int N, int K) {
  constexpr int MR = BM / 32, NR = BN / 32;
  __shared__ __align__(16) unsigned short As[BM * 64];
  __shared__ __align__(16) unsigned short Bs[BN * 64];
  const int tid = threadIdx.x;
  const long row0 = (long)blockIdx.x * BM;
  const long col0 = (long)blockIdx.y * BN;
  const int lane = tid & 63;
  const int wid = tid >> 6;
  const int ln15 = lane & 15, hi = lane >> 4;
  const int wr = (wid >> 1) * (BM / 2), wc = (wid & 1) * (BN / 2);
  const int sr = tid >> 3;
  const int sk = (tid & 7) * 8;
  f32x4 acc[MR][NR] = {};

  for (int k0 = 0; k0 < K; k0 += 64) {
#pragma unroll
    for (int c = 0; c < MR; ++c)
      gload_lds16(A  + (row0 + c * 32 + sr) * (long)K + k0 + sk, &As[(c * 256 + tid) * 8]);
#pragma unroll
    for (int c = 0; c < NR; ++c)
      gload_lds16(Bt + (col0 + c * 32 + sr) * (long)K + k0 + sk, &Bs[(c * 256 + tid) * 8]);
    __syncthreads();
#pragma unroll
    for (int kk = 0; kk < 64; kk += 32) {
      short8 a[MR], b[NR];
#pragma unroll
      for (int m = 0; m < MR; ++m)
        a[m] = *(const short8*)&As[(wr + m * 16 + ln15) * 64 + kk + hi * 8];
#pragma unroll
      for (int n = 0; n < NR; ++n)
        b[n] = *(const short8*)&Bs[(wc + n * 16 + ln15) * 64 + kk + hi * 8];
#pragma unroll
      for (int m = 0; m < MR; ++m)
#pragma unroll
        for (int n = 0; n < NR; ++n)
          acc[m][n] = __builtin_amdgcn_mfma_f32_16x16x32_bf16(a[m], b[n], acc[m][n], 0, 0, 0);
    }
    __syncthreads();
  }
#pragma unroll
  for (int m = 0; m < MR; ++m)
#pragma unroll
    for (int n = 0; n < NR; ++n)
#pragma unroll
      for (int r = 0; r < 4; ++r) {
        long row = row0 + wr + m * 16 + hi * 4 + r;
        long col = col0 + wc + n * 16 + ln15;
        C[row * N + col] = f2bf(acc[m][n][r]);
      }
}

// ---------- layer-1 aggregation: ONE WAVE PER NODE, 4-deep gather ILP ----------
// out_i = di*(sum_j dj*T_j + di*T_i) + b, relu. Lane holds 8 of 512 feats (uint4).
__global__ __launch_bounds__(256) void aggregate_relu(
    const unsigned short* __restrict__ T, const int* __restrict__ cnt,
    const int* __restrict__ adj, const float* __restrict__ bias,
    unsigned short* __restrict__ H) {
  const int w = threadIdx.x >> 6, lane = threadIdx.x & 63;
  const int i = blockIdx.x * 4 + w;
  __shared__ uint2 jw[4][CAP];           // {j, bits(dis_j)}
  const int n = cnt[i];
  for (int e0 = 0; e0 < n; e0 += 64)
    if (e0 + lane < n) {
      int j = adj[i * CAP + e0 + lane];
      float dj = rsqrtf((float)(cnt[j] + 1));
      jw[w][e0 + lane] = make_uint2((unsigned int)j, __float_as_uint(dj));
    }
  // independent self-row load issued early, consumed at the end
  const uint4 vs = *(const uint4*)&T[(size_t)i * 512 + lane * 8];
  __syncthreads();
  float a[8] = {};
  const float di = rsqrtf((float)(n + 1));
  int e = 0;
  for (; e + 4 <= n; e += 4) {
    const uint2 p0 = jw[w][e],     p1 = jw[w][e + 1];
    const uint2 p2 = jw[w][e + 2], p3 = jw[w][e + 3];
    const uint4 v0 = *(const uint4*)&T[(size_t)p0.x * 512 + lane * 8];
    const uint4 v1 = *(const uint4*)&T[(size_t)p1.x * 512 + lane * 8];
    const uint4 v2 = *(const uint4*)&T[(size_t)p2.x * 512 + lane * 8];
    const uint4 v3 = *(const uint4*)&T[(size_t)p3.x * 512 + lane * 8];
    const float w0 = __uint_as_float(p0.y), w1 = __uint_as_float(p1.y);
    const float w2 = __uint_as_float(p2.y), w3 = __uint_as_float(p3.y);
    a[0] += w0 * bflo(v0.x); a[1] += w0 * bfhi(v0.x);
    a[2] += w0 * bflo(v0.y); a[3] += w0 * bfhi(v0.y);
    a[4] += w0 * bflo(v0.z); a[5] += w0 * bfhi(v0.z);
    a[6] += w0 * bflo(v0.w); a[7] += w0 * bfhi(v0.w);
    a[0] += w1 * bflo(v1.x); a[1] += w1 * bfhi(v1.x);
    a[2] += w1 * bflo(v1.y); a[3] += w1 * bfhi(v1.y);
    a[4] += w1 * bflo(v1.z); a[5] += w1 * bfhi(v1.z);
    a[6] += w1 * bflo(v1.w); a[7] += w1 * bfhi(v1.w);
    a[0] += w2 * bflo(v2.x); a[1] += w2 * bfhi(v2.x);
    a[2] += w2 * bflo(v2.y); a[3] += w2 * bfhi(v2.y);
    a[4] += w2 * bflo(v2.z); a[5] += w2 * bfhi(v2.z);
    a[6] += w2 * bflo(v2.w); a[7] += w2 * bfhi(v2.w);
    a[0] += w3 * bflo(v3.x); a[1] += w3 * bfhi(v3.x);
    a[2] += w3 * bflo(v3.y); a[3] += w3 * bfhi(v3.y);
    a[4] += w3 * bflo(v3.z); a[5] += w3 * bfhi(v3.z);
    a[6] += w3 * bflo(v3.w); a[7] += w3 * bfhi(v3.w);
  }
  for (; e < n; ++e) {
    const uint2 p0 = jw[w][e];
    const uint4 v0 = *(const uint4*)&T[(size_t)p0.x * 512 + lane * 8];
    const float w0 = __uint_as_float(p0.y);
    a[0] += w0 * bflo(v0.x); a[1] += w0 * bfhi(v0.x);
    a[2] += w0 * bflo(v0.y); a[3] += w0 * bfhi(v0.y);
    a[4] += w0 * bflo(v0.z); a[5] += w0 * bfhi(v0.z);
    a[6] += w0 * bflo(v0.w); a[7] += w0 * bfhi(v0.w);
  }
  {  // self-loop (+I), stacks with any explicit self-edge handled in the loop
    a[0] += di * bflo(vs.x); a[1] += di * bfhi(vs.x);
    a[2] += di * bflo(vs.y); a[3] += di * bfhi(vs.y);
    a[4] += di * bflo(vs.z); a[5] += di * bfhi(vs.z);
    a[6] += di * bflo(vs.w); a[7] += di * bfhi(vs.w);
  }
  const float4 b0 = *(const float4*)&bias[lane * 8];
  const float4 b1 = *(const float4*)&bias[lane * 8 + 4];
  float h[8];
  h[0] = fmaxf(di * a[0] + b0.x, 0.f); h[1] = fmaxf(di * a[1] + b0.y, 0.f);
  h[2] = fmaxf(di * a[2] + b0.z, 0.f); h[3] = fmaxf(di * a[3] + b0.w, 0.f);
  h[4] = fmaxf(di * a[4] + b1.x, 0.f); h[5] = fmaxf(di * a[5] + b1.y, 0.f);
  h[6] = fmaxf(di * a[6] + b1.z, 0.f); h[7] = fmaxf(di * a[7] + b1.w, 0.f);
  uint4 o;
  o.x = (unsigned int)f2bf(h[0]) | ((unsigned int)f2bf(h[1]) << 16);
  o.y = (unsigned int)f2bf(h[2]) | ((unsigned int)f2bf(h[3]) << 16);
  o.z = (unsigned int)f2bf(h[4]) | ((unsigned int)f2bf(h[5]) << 16);
  o.w = (unsigned int)f2bf(h[6]) | ((unsigned int)f2bf(h[7]) << 16);
  *(uint4*)&H[(size_t)i * 512 + lane * 8] = o;
}

// ---------- layer-2 aggregation: ONE WAVE PER NODE (256 feats), 4-deep ILP ----------
__global__ __launch_bounds__(256) void aggregate_out(
    const unsigned short* __restrict__ T, const int* __restrict__ cnt,
    const int* __restrict__ adj, const float* __restrict__ bias,
    float* __restrict__ out) {
  const int w = threadIdx.x >> 6, lane = threadIdx.x & 63;
  const int i = blockIdx.x * 4 + w;
  __shared__ uint2 jw[4][CAP];
  const int n = cnt[i];
  for (int e0 = 0; e0 < n; e0 += 64)
    if (e0 + lane < n) {
      int j = adj[i * CAP + e0 + lane];
      float dj = rsqrtf((float)(cnt[j] + 1));
      jw[w][e0 + lane] = make_uint2((unsigned int)j, __float_as_uint(dj));
    }
  const uint2 vs = *(const uint2*)&T[(size_t)i * 256 + lane * 4];
  __syncthreads();
  float a[4] = {};
  const float di = rsqrtf((float)(n + 1));
  int e = 0;
  for (; e + 4 <= n; e += 4) {
    const uint2 p0 = jw[w][e],     p1 = jw[w][e + 1];
    const uint2 p2 = jw[w][e + 2], p3 = jw[w][e + 3];
    const uint2 v0 = *(const uint2*)&T[(size_t)p0.x * 256 + lane * 4];
    const uint2 v1 = *(const uint2*)&T[(size_t)p1.x * 256 + lane * 4];
    const uint2 v2 = *(const uint2*)&T[(size_t)p2.x * 256 + lane * 4];
    const uint2 v3 = *(const uint2*)&T[(size_t)p3.x * 256 + lane * 4];
    const float w0 = __uint_as_float(p0.y), w1 = __uint_as_float(p1.y);
    const float w2 = __uint_as_float(p2.y), w3 = __uint_as_float(p3.y);
    a[0] += w0 * bflo(v0.x); a[1] += w0 * bfhi(v0.x);
    a[2] += w0 * bflo(v0.y); a[3] += w0 * bfhi(v0.y);
    a[0] += w1 * bflo(v1.x); a[1] += w1 * bfhi(v1.x);
    a[2] += w1 * bflo(v1.y); a[3] += w1 * bfhi(v1.y);
    a[0] += w2 * bflo(v2.x); a[1] += w2 * bfhi(v2.x);
    a[2] += w2 * bflo(v2.y); a[3] += w2 * bfhi(v2.y);
    a[0] += w3 * bflo(v3.x); a[1] += w3 * bfhi(v3.x);
    a[2] += w3 * bflo(v3.y); a[3] += w3 * bfhi(v3.y);
  }
  for (; e < n; ++e) {
    const uint2 p0 = jw[w][e];
    const uint2 v0 = *(const uint2*)&T[(size_t)p0.x * 256 + lane * 4];
    const float w0 = __uint_as_float(p0.y);
    a[0] += w0 * bflo(v0.x); a[1] += w0 * bfhi(v0.x);
    a[2] += w0 * bflo(v0.y); a[3] += w0 * bfhi(v0.y);
  }
  {
    a[0] += di * bflo(vs.x); a[1] += di * bfhi(vs.x);
    a[2] += di * bflo(vs.y); a[3] += di * bfhi(vs.y);
  }
  const float4 bb = *(const float4*)&bias[lane * 4];
  float4 o;
  o.x = di * a[0] + bb.x;
  o.y = di * a[1] + bb.y;
  o.z = di * a[2] + bb.z;
  o.w = di * a[3] + bb.w;
  *(float4*)&out[(size_t)i * 256 + lane * 4] = o;
}

extern "C" void kernel_launch(void* const* d_in, const int* in_sizes, int n_in,
                              void* d_out, int out_size, void* d_ws, size_t ws_size,
                              hipStream_t stream) {
  const float* x  = (const float*)d_in[0];
  const int*   ei = (const int*)d_in[1];
  const float* W1 = (const float*)d_in[2];
  const float* b1 = (const float*)d_in[3];
  const float* W2 = (const float*)d_in[4];
  const float* b2 = (const float*)d_in[5];
  float* out = (float*)d_out;

  char* ws = (char*)d_ws;
  unsigned int* bitmap = (unsigned int*)ws;  ws += 8388608;              // 8192^2 bits
  int* cnt   = (int*)ws;                     ws += 32768;
  int* adj   = (int*)ws;                     ws += (size_t)N_NODES * CAP * 4;
  unsigned short* Xb  = (unsigned short*)ws; ws += (size_t)N_NODES * IN_F * 2;
  unsigned short* W1t = (unsigned short*)ws; ws += (size_t)IN_F * HID * 2;
  unsigned short* W2t = (unsigned short*)ws; ws += (size_t)HID * OUT_F * 2;
  unsigned short* T1  = (unsigned short*)ws; ws += (size_t)N_NODES * HID * 2;
  unsigned short* H   = (unsigned short*)ws; ws += (size_t)N_NODES * HID * 2;
  unsigned short* T2  = (unsigned short*)ws; ws += (size_t)N_NODES * OUT_F * 2;

  hipMemsetAsync(bitmap, 0, 8388608 + 32768, stream);  // bitmap + cnt contiguous

  prep_all<<<NB_CVT + NB_W1T + NB_W2T + NB_EDGE, 256, 0, stream>>>(
      x, W1, W2, ei, Xb, W1t, W2t, bitmap, cnt, adj);

  // layer 1: T1 = X @ W1 ; H = relu(Ahat * T1 + b1)
  gemm_bt<128, 64><<<dim3(N_NODES / 128, HID / 64), 256, 0, stream>>>(Xb, W1t, T1, N_NODES, HID, IN_F);
  aggregate_relu<<<N_NODES / 4, 256, 0, stream>>>(T1, cnt, adj, b1, H);

  // layer 2: T2 = H @ W2 ; out = Ahat * T2 + b2
  gemm_bt<64, 64><<<dim3(N_NODES / 64, OUT_F / 64), 256, 0, stream>>>(H, W2t, T2, N_NODES, OUT_F, HID);
  aggregate_out<<<N_NODES / 4, 256, 0, stream>>>(T2, cnt, adj, b2, out);
}